// Round 17
// baseline (434.734 us; speedup 1.0000x reference)
//
#include <hip/hip_runtime.h>
#include <math.h>

#define BB 256   // batch
#define CC 64    // channels / graph nodes
#define LL 512   // series length
#define HH 128   // gcn hidden
#define G3 384   // 3*gru_dim
#define NC 8
#define AT 64
#define CL1 519
#define CL2 527
#define CL3 535
#define THRESH 0.02f

typedef _Float16 h2 __attribute__((ext_vector_type(2)));
typedef _Float16 f16x8 __attribute__((ext_vector_type(8)));
typedef float f32x4 __attribute__((ext_vector_type(4)));
union HU { unsigned int u; h2 h; float f; };
union BU { uint4 u; f16x8 h; };

__device__ inline float warp_red_sum(float v) {
  #pragma unroll
  for (int o = 32; o > 0; o >>= 1) v += __shfl_down(v, o, 64);
  return v;
}

__device__ inline float fdot2f(h2 a, h2 b, float c) {
#if __has_builtin(__builtin_amdgcn_fdot2)
  return __builtin_amdgcn_fdot2(a, b, c, false);
#else
  float r;
  asm volatile("v_dot2_f32_f16 %0, %1, %2, %3" : "=v"(r) : "v"(a), "v"(b), "v"(c));
  return r;
#endif
}
__device__ inline h2 asH2(float f) { HU u; u.f = f; return u.h; }
__device__ inline h2 uH2(unsigned int x) { HU u; u.u = x; return u.h; }
__device__ inline unsigned int packh(float a, float b) {
  HU u; h2 t; t.x = (_Float16)a; t.y = (_Float16)b; u.h = t; return u.u;
}
// hardware exp2 / rcp (1-ulp; continuous paths only, never near discrete thresholds)
__device__ inline float vexp2(float x) { float r; asm("v_exp_f32 %0, %1" : "=v"(r) : "v"(x)); return r; }
__device__ inline float vrcp(float x)  { float r; asm("v_rcp_f32 %0, %1" : "=v"(r) : "v"(x)); return r; }
__device__ inline float fsigm(float x) { return vrcp(1.f + vexp2(-1.44269504f * x)); }
__device__ inline float ftanh(float x) { return 1.f - 2.f * vrcp(vexp2(2.88539008f * x) + 1.f); }

// conv weights -> MFMA B-fragment-linear layout (tap decode)
__device__ inline void packw_one(const float* __restrict__ W, unsigned int* __restrict__ out,
                                 int idx, int cinlog, int KS) {
  int w_ = idx & 3, l = (idx >> 2) & 63, n = (idx >> 8) & 7, c = idx >> 11;
  int CIN = 1 << cinlog;
  int oc = n * 16 + (l & 15);
  int k0 = c * 32 + ((l >> 4) << 3) + 2 * w_;
  int t0 = k0 >> cinlog, ci0 = k0 & (CIN - 1);
  int t1 = (k0 + 1) >> cinlog, ci1 = (k0 + 1) & (CIN - 1);
  out[idx] = packh(W[(size_t)oc * CIN * KS + ci0 * KS + t0],
                   W[(size_t)oc * CIN * KS + ci1 * KS + t1]);
}

// ---- ONE pack kernel: gcn weights + wih^T + whh + conv weights + gat wa vectors ----
__global__ void k_packall(const float* __restrict__ gcnW0, const float* __restrict__ gcnW1,
                          const float* __restrict__ gcnW2, const float* __restrict__ wih,
                          const float* __restrict__ whh,
                          const float* __restrict__ c1W, const float* __restrict__ c2W,
                          const float* __restrict__ c3W,
                          const float* __restrict__ gatW, const float* __restrict__ a1,
                          const float* __restrict__ a2,
                          unsigned int* gw1h, unsigned int* gw2h, unsigned int* gw3h,
                          unsigned int* wihTh, unsigned int* wpk,
                          unsigned int* wt1h, unsigned int* wt2h, unsigned int* wt3h,
                          float* wa1, float* wa2) {
  int idx = blockIdx.x * 256 + threadIdx.x;
  if (idx < 32768) {
    int w_ = idx & 3, l = (idx >> 2) & 63, n = (idx >> 8) & 7, c = idx >> 11;
    int k0 = c * 32 + ((l >> 4) << 3) + 2 * w_;
    int col = n * 16 + (l & 15);
    gw1h[idx] = packh(gcnW0[k0 * 128 + col], gcnW0[(k0 + 1) * 128 + col]);
  } else if (idx < 40960) {
    int t = idx - 32768;
    int w_ = t & 3, l = (t >> 2) & 63, n = (t >> 8) & 7, c = t >> 11;
    int k0 = c * 32 + ((l >> 4) << 3) + 2 * w_;
    int col = n * 16 + (l & 15);
    gw2h[t] = packh(gcnW1[k0 * 128 + col], gcnW1[(k0 + 1) * 128 + col]);
  } else if (idx < 49152) {
    int t = idx - 40960;
    int w_ = t & 3, l = (t >> 2) & 63, n = (t >> 8) & 7, c = t >> 11;
    int k0 = c * 32 + ((l >> 4) << 3) + 2 * w_;
    int col = n * 16 + (l & 15);
    gw3h[t] = packh(gcnW2[k0 * 128 + col], gcnW2[(k0 + 1) * 128 + col]);
  } else if (idx < 147456) {
    // B = wih^T: B[k][n] = wih[n][k]; wih [384][512]; N16=24
    int t = idx - 49152;
    int w_ = t & 3, l = (t >> 2) & 63;
    int nfc = t >> 8;
    int n = nfc % 24, c = nfc / 24;
    int k0 = c * 32 + ((l >> 4) << 3) + 2 * w_;
    int col = n * 16 + (l & 15);
    wihTh[t] = packh(wih[col * 512 + k0], wih[col * 512 + k0 + 1]);
  } else if (idx < 172032) {
    int t = idx - 147456; int j = t & 127, rk = t >> 7;
    int r = rk >> 6, k2 = rk & 63;
    const float* src = whh + (size_t)(j + 128 * r) * 128 + 2 * k2;
    wpk[t] = packh(src[0], src[1]);
  } else if (idx < 204800) {
    packw_one(c1W, wt1h, idx - 172032, 6, 8);
  } else if (idx < 245760) {
    packw_one(c2W, wt2h, idx - 204800, 7, 5);
  } else if (idx < 270336) {
    packw_one(c3W, wt3h, idx - 245760, 7, 3);
  } else if (idx < 270848) {
    int l = idx - 270336;
    const float* row = gatW + l * LL;
    float s1 = 0.f, s2 = 0.f;
    for (int k = 0; k < LL; k++) { float w = row[k]; s1 += w * a1[k]; s2 += w * a2[k]; }
    wa1[l] = s1; wa2[l] = s2;
  }
}

// ---- fused GAT: per-sample block; row dots (4 lanes/row) + softmax + mask + dinv ----
__global__ __launch_bounds__(256) void k_gat(const float* __restrict__ x,
                                             const float* __restrict__ wa1,
                                             const float* __restrict__ wa2,
                                             float* __restrict__ mask,
                                             float* __restrict__ dinv) {
  __shared__ float h1s[64], h2s[64];
  int b = blockIdx.x, tid = threadIdx.x;
  int i = tid >> 2, q = tid & 3;
  const float* xr = x + ((size_t)b * 64 + i) * LL + q * 128;
  float s1 = 0.f, s2 = 0.f;
  #pragma unroll 4
  for (int k = 0; k < 128; k += 4) {
    float4 xv = *(const float4*)&xr[k];
    float4 w1 = *(const float4*)&wa1[q * 128 + k];
    float4 w2 = *(const float4*)&wa2[q * 128 + k];
    s1 += xv.x * w1.x + xv.y * w1.y + xv.z * w1.z + xv.w * w1.w;
    s2 += xv.x * w2.x + xv.y * w2.y + xv.z * w2.z + xv.w * w2.w;
  }
  s1 += __shfl_xor(s1, 1, 64); s1 += __shfl_xor(s1, 2, 64);
  s2 += __shfl_xor(s2, 1, 64); s2 += __shfl_xor(s2, 2, 64);
  if (q == 0) { h1s[i] = s1; h2s[i] = s2; }
  __syncthreads();
  float hi = h1s[i];
  float e[16];
  float mx = -3.4e38f;
  #pragma unroll
  for (int u = 0; u < 16; u++) {
    float v = hi + h2s[q * 16 + u];
    v = v < 0.f ? 0.2f * v : v;
    e[u] = v;
    mx = fmaxf(mx, v);
  }
  mx = fmaxf(mx, __shfl_xor(mx, 1, 64));
  mx = fmaxf(mx, __shfl_xor(mx, 2, 64));
  float sm = 0.f;
  #pragma unroll
  for (int u = 0; u < 16; u++) { e[u] = expf(e[u] - mx); sm += e[u]; }
  sm += __shfl_xor(sm, 1, 64); sm += __shfl_xor(sm, 2, 64);
  float cnt = 0.f;
  #pragma unroll
  for (int u = 0; u < 16; u++) {
    float mval = (e[u] / sm > THRESH) ? 1.f : 0.f;
    mask[((size_t)b * 64 + i) * 64 + q * 16 + u] = mval;
    cnt += mval;
  }
  cnt += __shfl_xor(cnt, 1, 64); cnt += __shfl_xor(cnt, 2, 64);
  if (q == 0) dinv[b * 64 + i] = 1.f / sqrtf(cnt + 1.f);
}

// ---------------- MFMA GEMM: C[M,N] = A[M,K](fp32) @ Bf(fragment-packed f16) ----------------
__global__ __launch_bounds__(256) void k_gmfma(const float* __restrict__ A,
                                               const uint4* __restrict__ Bf,
                                               void* __restrict__ Cv,
                                               int M, int N, int K, int out16) {
  __shared__ _Float16 as[2][64 * 64];
  int nwg = gridDim.x, bid = blockIdx.x;
  int lb = (bid & 7) * (nwg >> 3) + (bid >> 3);
  int nbn = N >> 7;
  int bm = lb / nbn, bn = lb - bm * nbn;
  int m0 = bm * 64;
  int tid = threadIdx.x, l = tid & 63, w = tid >> 6;
  int NKT = K >> 6, NC2 = K >> 5, N16 = N >> 4;
  int nf0 = bn * 8 + 2 * w, nf1 = nf0 + 1;
  int ar = tid >> 2;
  int ac = (tid & 3) * 16;
  float4 rg[4];
  auto stageA = [&](int kt) {
    const float* src = &A[(size_t)(m0 + ar) * K + kt * 64 + ac];
    rg[0] = *(const float4*)&src[0];
    rg[1] = *(const float4*)&src[4];
    rg[2] = *(const float4*)&src[8];
    rg[3] = *(const float4*)&src[12];
  };
  auto commitA = [&](int buf) {
    int s0 = (tid & 3) * 2;
    int phys0 = (s0 ^ (ar & 7)) * 8;
    int phys1 = ((s0 + 1) ^ (ar & 7)) * 8;
    uint4 v0, v1;
    v0.x = packh(rg[0].x, rg[0].y); v0.y = packh(rg[0].z, rg[0].w);
    v0.z = packh(rg[1].x, rg[1].y); v0.w = packh(rg[1].z, rg[1].w);
    v1.x = packh(rg[2].x, rg[2].y); v1.y = packh(rg[2].z, rg[2].w);
    v1.z = packh(rg[3].x, rg[3].y); v1.w = packh(rg[3].z, rg[3].w);
    *(uint4*)&as[buf][ar * 64 + phys0] = v0;
    *(uint4*)&as[buf][ar * 64 + phys1] = v1;
  };
  f32x4 acc[4][2];
  #pragma unroll
  for (int m = 0; m < 4; m++) {
    acc[m][0] = (f32x4){0.f, 0.f, 0.f, 0.f};
    acc[m][1] = (f32x4){0.f, 0.f, 0.f, 0.f};
  }
  stageA(0); commitA(0);
  uint4 bc0 = Bf[(size_t)nf0 * 64 + l];
  uint4 bc1 = Bf[(size_t)nf1 * 64 + l];
  __syncthreads();
  for (int c = 0; c < NC2; c++) {
    int kt = c >> 1, half = c & 1;
    if (half == 0 && kt + 1 < NKT) stageA(kt + 1);
    uint4 pn0 = bc0, pn1 = bc1;
    if (c + 1 < NC2) {
      pn0 = Bf[(size_t)((c + 1) * N16 + nf0) * 64 + l];
      pn1 = Bf[(size_t)((c + 1) * N16 + nf1) * 64 + l];
    }
    int slotbase = half * 4 + (l >> 4);
    f16x8 a[4];
    #pragma unroll
    for (int m = 0; m < 4; m++) {
      int row = m * 16 + (l & 15);
      int phys = slotbase ^ (row & 7);
      a[m] = *(const f16x8*)&as[kt & 1][row * 64 + phys * 8];
    }
    BU u0, u1; u0.u = bc0; u1.u = bc1;
    #pragma unroll
    for (int m = 0; m < 4; m++) {
      acc[m][0] = __builtin_amdgcn_mfma_f32_16x16x32_f16(a[m], u0.h, acc[m][0], 0, 0, 0);
      acc[m][1] = __builtin_amdgcn_mfma_f32_16x16x32_f16(a[m], u1.h, acc[m][1], 0, 0, 0);
    }
    if (half == 1 && kt + 1 < NKT) {
      commitA((kt + 1) & 1);
      __syncthreads();
    }
    bc0 = pn0; bc1 = pn1;
  }
  if (out16) {
    _Float16* Ch = (_Float16*)Cv;
    #pragma unroll
    for (int n = 0; n < 2; n++) {
      int col = (nf0 + n) * 16 + (l & 15);
      #pragma unroll
      for (int m = 0; m < 4; m++) {
        #pragma unroll
        for (int i = 0; i < 4; i++)
          Ch[(size_t)(m0 + m * 16 + (l >> 4) * 4 + i) * N + col] = (_Float16)acc[m][n][i];
      }
    }
  } else {
    float* Cf = (float*)Cv;
    #pragma unroll
    for (int n = 0; n < 2; n++) {
      int col = (nf0 + n) * 16 + (l & 15);
      #pragma unroll
      for (int m = 0; m < 4; m++) {
        #pragma unroll
        for (int i = 0; i < 4; i++)
          Cf[(size_t)(m0 + m * 16 + (l >> 4) * 4 + i) * N + col] = acc[m][n][i];
      }
    }
  }
}

// ---- fused GCN-aggregation + SAGPool: per-sample block ----
template<int N, int KK>
__global__ __launch_bounds__(256) void k_gcnpool(const float* __restrict__ xw,
                                                 const float* __restrict__ mask,
                                                 const float* __restrict__ dinv,
                                                 const float* __restrict__ bias,
                                                 const float* __restrict__ w1,
                                                 const float* __restrict__ w2,
                                                 const float* __restrict__ pb,
                                                 float* gp, float* mnext, float* dnext,
                                                 float* __restrict__ r, int accum) {
  constexpr int RPT = (N >= 32) ? (N / 32) : 1;   // rows per thread
  constexpr int NRG = N / RPT;                    // row groups (<= 32)
  __shared__ float xs[N * 132];
  __shared__ float ms[N * 65];
  __shared__ float dv[64];
  __shared__ float d1s[64], d2s[64], sv[64], vals[32], tvs[32];
  __shared__ int idxs[32];
  int b = blockIdx.x, tid = threadIdx.x;
  for (int q = tid; q < N * 32; q += 256) {
    int i = q >> 5, fo = (q & 31) * 4;
    *(float4*)&xs[i * 132 + fo] = *(const float4*)&xw[((size_t)b * N + i) * 128 + fo];
  }
  for (int q = tid; q < N * N; q += 256) {
    int row = q / N, u = q - row * N;
    ms[row * 65 + u] = mask[(size_t)(b * N + row) * N + u];
  }
  if (tid < N) dv[tid] = dinv[b * N + tid];
  __syncthreads();
  for (int q = tid; q < N * 32; q += 256) {
    int i = q >> 5, fo = (q & 31) * 4;
    float4 v = *(float4*)&xs[i * 132 + fo];
    float d = dv[i];
    v.x *= d; v.y *= d; v.z *= d; v.w *= d;
    *(float4*)&xs[i * 132 + fo] = v;
  }
  __syncthreads();
  int ri = tid >> 3, fq = tid & 7, f0 = fq * 16;
  float g[RPT][16];
  if (ri < NRG) {
    float acc[RPT][16];
    #pragma unroll
    for (int p = 0; p < RPT; p++)
      #pragma unroll
      for (int e = 0; e < 16; e++) acc[p][e] = 0.f;
    for (int j = 0; j < N; j++) {
      float4 xa = *(const float4*)&xs[j * 132 + f0];
      float4 xb = *(const float4*)&xs[j * 132 + f0 + 4];
      float4 xc = *(const float4*)&xs[j * 132 + f0 + 8];
      float4 xd = *(const float4*)&xs[j * 132 + f0 + 12];
      #pragma unroll
      for (int p = 0; p < RPT; p++) {
        float m = ms[(ri * RPT + p) * 65 + j];
        acc[p][0] += m * xa.x;  acc[p][1] += m * xa.y;
        acc[p][2] += m * xa.z;  acc[p][3] += m * xa.w;
        acc[p][4] += m * xb.x;  acc[p][5] += m * xb.y;
        acc[p][6] += m * xb.z;  acc[p][7] += m * xb.w;
        acc[p][8] += m * xc.x;  acc[p][9] += m * xc.y;
        acc[p][10] += m * xc.z; acc[p][11] += m * xc.w;
        acc[p][12] += m * xd.x; acc[p][13] += m * xd.y;
        acc[p][14] += m * xd.z; acc[p][15] += m * xd.w;
      }
    }
    float bz[16];
    #pragma unroll
    for (int e = 0; e < 16; e++) bz[e] = bias[f0 + e];
    #pragma unroll
    for (int p = 0; p < RPT; p++) {
      int i = ri * RPT + p;
      float di = dv[i];
      float4 sa = *(const float4*)&xs[i * 132 + f0];
      float4 sb = *(const float4*)&xs[i * 132 + f0 + 4];
      float4 sc = *(const float4*)&xs[i * 132 + f0 + 8];
      float4 sd = *(const float4*)&xs[i * 132 + f0 + 12];
      float sx[16] = {sa.x, sa.y, sa.z, sa.w, sb.x, sb.y, sb.z, sb.w,
                      sc.x, sc.y, sc.z, sc.w, sd.x, sd.y, sd.z, sd.w};
      #pragma unroll
      for (int e = 0; e < 16; e++) {
        float y = di * (sx[e] + acc[p][e]) + bz[e];
        g[p][e] = y > 0.f ? y : 0.f;
      }
    }
  }
  __syncthreads();
  if (ri < NRG) {
    #pragma unroll
    for (int p = 0; p < RPT; p++) {
      int i = ri * RPT + p;
      float4 va = {g[p][0], g[p][1], g[p][2], g[p][3]};
      float4 vb = {g[p][4], g[p][5], g[p][6], g[p][7]};
      float4 vc = {g[p][8], g[p][9], g[p][10], g[p][11]};
      float4 vd = {g[p][12], g[p][13], g[p][14], g[p][15]};
      *(float4*)&xs[i * 132 + f0] = va;
      *(float4*)&xs[i * 132 + f0 + 4] = vb;
      *(float4*)&xs[i * 132 + f0 + 8] = vc;
      *(float4*)&xs[i * 132 + f0 + 12] = vd;
    }
  }
  __syncthreads();
  {
    int i = tid >> 2, q4 = tid & 3;
    if (i < N) {
      float a = 0.f, c = 0.f;
      const float* gr = &xs[i * 132 + q4 * 32];
      const float* w1p = &w1[q4 * 32];
      const float* w2p = &w2[q4 * 32];
      for (int d = 0; d < 32; d++) { float v = gr[d]; a += v * w1p[d]; c += v * w2p[d]; }
      a += __shfl_xor(a, 1, 64); a += __shfl_xor(a, 2, 64);
      c += __shfl_xor(c, 1, 64); c += __shfl_xor(c, 2, 64);
      if (q4 == 0) { d1s[i] = a; d2s[i] = c; }
    }
  }
  __syncthreads();
  if (tid < N) {
    const float* mr = &ms[tid * 65];
    float s = d1s[tid] + pb[0];
    for (int j = 0; j < N; j++) s += mr[j] * d2s[j];
    sv[tid] = s;
  }
  __syncthreads();
  if (tid < 64) {
    float myv = (tid < N) ? sv[tid] : -3.4e38f;
    int alive = (tid < N) ? 1 : 0;
    for (int t = 0; t < KK; t++) {
      float cv = alive ? myv : -3.4e38f;
      int ci = tid;
      #pragma unroll
      for (int o = 32; o > 0; o >>= 1) {
        float ov = __shfl_xor(cv, o, 64);
        int oi = __shfl_xor(ci, o, 64);
        if (ov > cv || (ov == cv && oi < ci)) { cv = ov; ci = oi; }
      }
      if (tid == ci) alive = 0;
      if (tid == 0) { idxs[t] = ci; vals[t] = cv; }
    }
  }
  __syncthreads();
  if (tid < KK) tvs[tid] = tanhf(vals[tid]);
  __syncthreads();
  if (tid < HH) {
    float mx = -3.4e38f, sm = 0.f;
    for (int t = 0; t < KK; t++) {
      float v = xs[idxs[t] * 132 + tid] * tvs[t];
      if (gp) gp[(size_t)(b * KK + t) * HH + tid] = v;
      mx = fmaxf(mx, v); sm += v;
    }
    float mres = sm / (float)KK;
    if (accum) {
      r[b * 256 + tid] += mx;
      r[b * 256 + 128 + tid] += mres;
    } else {
      r[b * 256 + tid] = mx;
      r[b * 256 + 128 + tid] = mres;
    }
  }
  for (int q = tid; q < KK * KK; q += 256) {
    int t = q / KK, u = q - t * KK;
    mnext[(size_t)(b * KK + t) * KK + u] = ms[idxs[t] * 65 + idxs[u]];
  }
  if (dnext && tid < KK) {
    float s = 0.f;
    for (int u = 0; u < KK; u++) s += ms[idxs[tid] * 65 + idxs[u]];
    dnext[b * KK + tid] = 1.0f / sqrtf(s + 1.0f);
  }
}

// GRU recurrence: 256 threads/block, K-split pairs; f32 gi; ys f16 out.
__global__ __launch_bounds__(256, 1) void k_gru(const float* __restrict__ gi,
                                                const unsigned int* __restrict__ wpk,
                                                const float* __restrict__ bhh,
                                                const float* __restrict__ bih,
                                                _Float16* __restrict__ ys) {
  __shared__ _Float16 hb[2][128];
  int c = blockIdx.x;
  int j = threadIdx.x >> 1, half = threadIdx.x & 1;
  int kb = half * 32;
  h2 w0[32], w1[32], w2[32];
  #pragma unroll
  for (int kk = 0; kk < 32; kk++) { HU u; u.u = wpk[(kb + kk) * 128 + j]; w0[kk] = u.h; }
  #pragma unroll
  for (int kk = 0; kk < 32; kk++) { HU u; u.u = wpk[(64 + kb + kk) * 128 + j]; w1[kk] = u.h; }
  #pragma unroll
  for (int kk = 0; kk < 32; kk++) { HU u; u.u = wpk[(128 + kb + kk) * 128 + j]; w2[kk] = u.h; }
  float bh0 = bhh[j], bh1 = bhh[j + 128], bh2 = bhh[j + 256];
  float bi0 = bih[j], bi1 = bih[j + 128], bi2 = bih[j + 256];
  float hprev = 0.f;
  if (half == 0) hb[0][j] = (_Float16)0.f;
  __syncthreads();
  const float* gbase = gi + (size_t)c * G3 + j;
  float g0 = gbase[0], g1 = gbase[128], g2 = gbase[256];
  int cur = 0;
  for (int b = 0; b < BB; b++) {
    float n0 = 0.f, n1 = 0.f, n2 = 0.f;
    if (b + 1 < BB) {
      const float* gn = gbase + (size_t)(b + 1) * CC * G3;
      n0 = gn[0]; n1 = gn[128]; n2 = gn[256];
    }
    float a0a = 0.f, a0b = 0.f, a1a = 0.f, a1b = 0.f, a2a = 0.f, a2b = 0.f;
    #pragma unroll
    for (int q = 0; q < 8; q++) {
      float4 hv = *(const float4*)&hb[cur][half * 64 + q * 8];
      h2 h0 = asH2(hv.x), h1 = asH2(hv.y), h2v = asH2(hv.z), h3 = asH2(hv.w);
      a0a = fdot2f(w0[q * 4 + 0], h0, a0a); a0b = fdot2f(w0[q * 4 + 1], h1, a0b);
      a0a = fdot2f(w0[q * 4 + 2], h2v, a0a); a0b = fdot2f(w0[q * 4 + 3], h3, a0b);
      a1a = fdot2f(w1[q * 4 + 0], h0, a1a); a1b = fdot2f(w1[q * 4 + 1], h1, a1b);
      a1a = fdot2f(w1[q * 4 + 2], h2v, a1a); a1b = fdot2f(w1[q * 4 + 3], h3, a1b);
      a2a = fdot2f(w2[q * 4 + 0], h0, a2a); a2b = fdot2f(w2[q * 4 + 1], h1, a2b);
      a2a = fdot2f(w2[q * 4 + 2], h2v, a2a); a2b = fdot2f(w2[q * 4 + 3], h3, a2b);
    }
    float A0 = a0a + a0b, A1 = a1a + a1b, A2 = a2a + a2b;
    A0 += __shfl_xor(A0, 1, 64);
    A1 += __shfl_xor(A1, 1, 64);
    A2 += __shfl_xor(A2, 1, 64);
    A0 += bh0; A1 += bh1; A2 += bh2;
    float rg = fsigm(g0 + bi0 + A0);
    float zg = fsigm(g1 + bi1 + A1);
    float ng = ftanh(g2 + bi2 + rg * A2);
    float hn = (1.f - zg) * ng + zg * hprev;
    hprev = hn;
    if (half == 0) {
      ys[(size_t)(b * CC + c) * 128 + j] = (_Float16)hn;
      hb[cur ^ 1][j] = (_Float16)hn;
    }
    asm volatile("s_waitcnt lgkmcnt(0)" ::: "memory");
    __builtin_amdgcn_s_barrier();
    cur ^= 1;
    g0 = n0; g1 = n1; g2 = n2;
  }
}

// ---------------- MFMA implicit-GEMM conv ----------------
template<int CIN, int KS, int DIL, int PAD, int LIN, int LOUT, int MODE>
__global__ __launch_bounds__(256) void k_cmfma(const void* __restrict__ inv,
                                               const uint4* __restrict__ Bf,
                                               const float* __restrict__ bias,
                                               void* __restrict__ outv, int b0) {
  constexpr int QN = CIN / 32;
  constexpr int NCH = KS * QN;
  constexpr int SLOTS = CIN / 8;
  constexpr int NT = (LOUT + 63) / 64;
  __shared__ _Float16 xs[72 * CIN];
  int nb = blockIdx.x / NT;
  int p0 = (blockIdx.x % NT) * 64;
  int tid = threadIdx.x;
  int l = tid & 63, w = tid >> 6;

  if constexpr (MODE == 0) {
    const float* src = (const float*)inv + (size_t)nb * CIN * LIN;
    for (int q = tid; q < (CIN / 2) * 72; q += 256) {
      int ci2 = q / 72, r = q % 72;
      int ci = 2 * ci2;
      int p = p0 - PAD + r;
      float v0 = 0.f, v1 = 0.f;
      if (p >= 0 && p < LIN) { v0 = src[ci * LIN + p]; v1 = src[(ci + 1) * LIN + p]; }
      int slot = ci >> 3;
      int phys = slot ^ (r & 7);
      *(unsigned int*)&xs[r * CIN + phys * 8 + (ci & 7)] = packh(v0, v1);
    }
  } else {
    const _Float16* src = (const _Float16*)inv + (size_t)nb * LIN * CIN;
    for (int q = tid; q < 72 * SLOTS; q += 256) {
      int r = q / SLOTS, s = q % SLOTS;
      int p = p0 - PAD + r;
      uint4 v = make_uint4(0u, 0u, 0u, 0u);
      if (p >= 0 && p < LIN) v = *(const uint4*)&src[(size_t)p * CIN + s * 8];
      int phys = s ^ (r & 7);
      *(uint4*)&xs[r * CIN + phys * 8] = v;
    }
  }
  __syncthreads();

  int n0 = 2 * w, n1 = n0 + 1;
  f32x4 acc[4][2];
  #pragma unroll
  for (int m = 0; m < 4; m++) {
    acc[m][0] = (f32x4){0.f, 0.f, 0.f, 0.f};
    acc[m][1] = (f32x4){0.f, 0.f, 0.f, 0.f};
  }
  uint4 bc0 = Bf[(size_t)(0 * 8 + n0) * 64 + l];
  uint4 bc1 = Bf[(size_t)(0 * 8 + n1) * 64 + l];
  for (int c = 0; c < NCH; c++) {
    uint4 bn0 = bc0, bn1 = bc1;
    if (c + 1 < NCH) {
      bn0 = Bf[(size_t)((c + 1) * 8 + n0) * 64 + l];
      bn1 = Bf[(size_t)((c + 1) * 8 + n1) * 64 + l];
    }
    int t = c / QN, q = c % QN;
    int slotbase = q * 4 + (l >> 4);
    f16x8 a[4];
    #pragma unroll
    for (int m = 0; m < 4; m++) {
      int r = m * 16 + (l & 15) + t * DIL;
      int phys = slotbase ^ (r & 7);
      a[m] = *(const f16x8*)&xs[r * CIN + phys * 8];
    }
    BU u0, u1; u0.u = bc0; u1.u = bc1;
    #pragma unroll
    for (int m = 0; m < 4; m++) {
      acc[m][0] = __builtin_amdgcn_mfma_f32_16x16x32_f16(a[m], u0.h, acc[m][0], 0, 0, 0);
      acc[m][1] = __builtin_amdgcn_mfma_f32_16x16x32_f16(a[m], u1.h, acc[m][1], 0, 0, 0);
    }
    bc0 = bn0; bc1 = bn1;
  }

  if constexpr (MODE == 2) {
    float* xcv = (float*)outv;
    #pragma unroll
    for (int n = 0; n < 2; n++) {
      int oc = (2 * w + n) * 16 + (l & 15);
      float bz = bias[oc];
      float s = 0.f;
      #pragma unroll
      for (int m = 0; m < 4; m++) {
        #pragma unroll
        for (int i = 0; i < 4; i++) {
          int pos = p0 + m * 16 + (l >> 4) * 4 + i;
          if (pos < LOUT) { float y = acc[m][n][i] + bz; s += y > 0.f ? y : 0.f; }
        }
      }
      s += __shfl_xor(s, 16, 64);
      s += __shfl_xor(s, 32, 64);
      if (l < 16) atomicAdd(&xcv[(size_t)(b0 + nb) * 128 + oc], s);
    }
  } else {
    _Float16* outp = (_Float16*)outv + (size_t)nb * LOUT * 128;
    #pragma unroll
    for (int n = 0; n < 2; n++) {
      int oc = (2 * w + n) * 16 + (l & 15);
      float bz = bias[oc];
      #pragma unroll
      for (int m = 0; m < 4; m++) {
        #pragma unroll
        for (int i = 0; i < 4; i++) {
          int pos = p0 + m * 16 + (l >> 4) * 4 + i;
          if (pos < LOUT) {
            float y = acc[m][n][i] + bz;
            outp[(size_t)pos * 128 + oc] = (_Float16)(y > 0.f ? y : 0.f);
          }
        }
      }
    }
  }
}

// fc0: fused GRU mean (ys f16) + atomic batch-norm column stats
__global__ void k_fc0(const float* __restrict__ xconv, const _Float16* __restrict__ ys,
                      const float* __restrict__ r, const float* __restrict__ W,
                      const float* __restrict__ bias, float* __restrict__ hm,
                      float* __restrict__ csum, float* __restrict__ csum2) {
  __shared__ float feat[512];
  int b = blockIdx.x, t = threadIdx.x;
  if (t < 128) {
    feat[t] = xconv[b * 128 + t] * (1.f / (float)CL3);
    const _Float16* yb = ys + (size_t)b * CC * 128 + t;
    float acc = 0.f;
    for (int c = 0; c < CC; c++) acc += (float)yb[c * 128];
    feat[128 + t] = acc / 64.f;
  }
  feat[256 + t] = r[b * 256 + t];
  __syncthreads();
  float acc = bias[t];
  for (int k = 0; k < 512; k++) acc += feat[k] * W[k * 256 + t];
  hm[b * 256 + t] = acc;
  atomicAdd(&csum[t], acc);
  atomicAdd(&csum2[t], acc * acc);
}

// fused batchnorm (from atomic stats) + leaky_relu + fc1
__global__ void k_fc1bn(const float* __restrict__ hm, const float* __restrict__ csum,
                        const float* __restrict__ csum2, const float* __restrict__ gamma,
                        const float* __restrict__ beta, const float* __restrict__ W,
                        const float* __restrict__ bias, float* __restrict__ z) {
  __shared__ float hs[256];
  int b = blockIdx.x, t = threadIdx.x;   // 128 threads
  for (int kk = t; kk < 256; kk += 128) {
    float v = hm[b * 256 + kk];
    float mean = csum[kk] * (1.f / 256.f);
    float var = csum2[kk] * (1.f / 256.f) - mean * mean;
    float y = gamma[kk] * (v - mean) * (1.f / sqrtf(var + 1e-5f)) + beta[kk];
    hs[kk] = y < 0.f ? 0.01f * y : y;
  }
  __syncthreads();
  float acc = bias[t];
  for (int k = 0; k < 256; k++) acc += hs[k] * W[k * 128 + t];
  z[b * 128 + t] = acc;
}

// attention logits: grid (8 classes x 4 sample-tiles of 64)
__global__ __launch_bounds__(256) void k_att1(const float* __restrict__ z,
                                              const float* __restrict__ W1,
                                              const float* __restrict__ b1,
                                              const float* __restrict__ W2,
                                              float* __restrict__ logits) {
  __shared__ float sa[32][64];
  __shared__ float sb[32][64];
  int c = blockIdx.x >> 2;
  int m0 = (blockIdx.x & 3) * 64;
  const float* B = W1 + (size_t)c * 128 * AT;
  int tx = threadIdx.x & 15, ty = threadIdx.x >> 4;
  float acc[4][4];
  #pragma unroll
  for (int i = 0; i < 4; i++)
    #pragma unroll
    for (int j = 0; j < 4; j++) acc[i][j] = 0.f;
  int arow = threadIdx.x >> 2;
  int acol = (threadIdx.x & 3) * 8;
  int brow = threadIdx.x >> 4;
  int bcol = (threadIdx.x & 15) * 4;
  for (int k0 = 0; k0 < 128; k0 += 32) {
    float4 av0 = *(const float4*)&z[(size_t)(m0 + arow) * 128 + k0 + acol];
    float4 av1 = *(const float4*)&z[(size_t)(m0 + arow) * 128 + k0 + acol + 4];
    float4 bv0 = *(const float4*)&B[(size_t)(k0 + brow) * AT + bcol];
    float4 bv1 = *(const float4*)&B[(size_t)(k0 + brow + 16) * AT + bcol];
    __syncthreads();
    sa[acol + 0][arow] = av0.x; sa[acol + 1][arow] = av0.y;
    sa[acol + 2][arow] = av0.z; sa[acol + 3][arow] = av0.w;
    sa[acol + 4][arow] = av1.x; sa[acol + 5][arow] = av1.y;
    sa[acol + 6][arow] = av1.z; sa[acol + 7][arow] = av1.w;
    *(float4*)&sb[brow][bcol] = bv0;
    *(float4*)&sb[brow + 16][bcol] = bv1;
    __syncthreads();
    #pragma unroll
    for (int kk = 0; kk < 32; kk++) {
      float4 a4 = *(const float4*)&sa[kk][ty * 4];
      float4 b4 = *(const float4*)&sb[kk][tx * 4];
      acc[0][0] += a4.x * b4.x; acc[0][1] += a4.x * b4.y; acc[0][2] += a4.x * b4.z; acc[0][3] += a4.x * b4.w;
      acc[1][0] += a4.y * b4.x; acc[1][1] += a4.y * b4.y; acc[1][2] += a4.y * b4.z; acc[1][3] += a4.y * b4.w;
      acc[2][0] += a4.z * b4.x; acc[2][1] += a4.z * b4.y; acc[2][2] += a4.z * b4.z; acc[2][3] += a4.z * b4.w;
      acc[3][0] += a4.w * b4.x; acc[3][1] += a4.w * b4.y; acc[3][2] += a4.w * b4.z; acc[3][3] += a4.w * b4.w;
    }
  }
  const float* b1c = b1 + c * AT;
  const float* w2c = W2 + c * AT;
  float w2v[4], b1v[4];
  #pragma unroll
  for (int j = 0; j < 4; j++) { w2v[j] = w2c[tx * 4 + j]; b1v[j] = b1c[tx * 4 + j]; }
  #pragma unroll
  for (int i = 0; i < 4; i++) {
    float s = 0.f;
    #pragma unroll
    for (int j = 0; j < 4; j++) s += tanhf(acc[i][j] + b1v[j]) * w2v[j];
    #pragma unroll
    for (int o = 8; o > 0; o >>= 1) s += __shfl_xor(s, o, 64);
    if (tx == 0) logits[c * 256 + m0 + ty * 4 + i] = s;
  }
}

// masked softmax over samples + prototype
__global__ void k_att2(const float* __restrict__ z, const int* __restrict__ labels,
                       const int* __restrict__ idx_train, int ntrain,
                       const float* __restrict__ logits, const float* __restrict__ b2,
                       float* __restrict__ protos) {
  __shared__ float wv[256], red[256];
  __shared__ int trainm[256];
  int c = blockIdx.x, n = threadIdx.x;
  trainm[n] = 0; __syncthreads();
  if (n < ntrain) trainm[idx_train[n]] = 1;
  __syncthreads();
  bool keep = trainm[n] && (labels[n] == c);
  float ml = keep ? (logits[c * 256 + n] + b2[c]) : -1e30f;
  red[n] = ml; __syncthreads();
  for (int s = 128; s > 0; s >>= 1) { if (n < s) red[n] = fmaxf(red[n], red[n + s]); __syncthreads(); }
  float mx = red[0]; __syncthreads();
  float e = expf(ml - mx);
  wv[n] = e; red[n] = e; __syncthreads();
  for (int s = 128; s > 0; s >>= 1) { if (n < s) red[n] += red[n + s]; __syncthreads(); }
  float ssum = red[0]; __syncthreads();
  wv[n] = wv[n] / ssum;
  __syncthreads();
  if (n < 128) {
    float p = 0.f;
    for (int q = 0; q < 256; q++) p += wv[q] * z[q * 128 + n];
    protos[c * 128 + n] = p;
  }
}

// distances; block BB does the prototype-pair term
__global__ void k_dist(const float* __restrict__ z, const float* __restrict__ protos,
                       float* __restrict__ dout) {
  if (blockIdx.x == BB) {
    int t = threadIdx.x;
    if (t < 64) {
      int i = t >> 3, jx = t & 7;
      float dot = 0.f, p2i = 0.f, p2j = 0.f;
      for (int d = 0; d < 128; d++) {
        float a = protos[i * 128 + d], bb2 = protos[jx * 128 + d];
        dot += a * bb2; p2i += a * a; p2j += bb2 * bb2;
      }
      float d2 = fmaxf(p2i + p2j - 2.f * dot, 1e-12f);
      float e = expf(-0.5f * sqrtf(d2));
      e = warp_red_sum(e);
      if (t == 0) dout[2048] = e / 28.f;
    }
    return;
  }
  __shared__ float zs[128], red[128];
  int n = blockIdx.x, t = threadIdx.x;
  zs[t] = z[n * 128 + t];
  red[t] = zs[t] * zs[t]; __syncthreads();
  for (int s = 64; s > 0; s >>= 1) { if (t < s) red[t] += red[t + s]; __syncthreads(); }
  float z2 = red[0];
  if (t < NC) {
    float dot = 0.f, p2 = 0.f;
    const float* pr = protos + t * 128;
    for (int d = 0; d < 128; d++) { float pv = pr[d]; dot += pv * zs[d]; p2 += pv * pv; }
    float d2 = fmaxf(z2 + p2 - 2.f * dot, 1e-12f);
    dout[n * NC + t] = expf(-0.5f * sqrtf(d2));
  }
}

extern "C" void kernel_launch(void* const* d_in, const int* in_sizes, int n_in,
                              void* d_out, int out_size, void* d_ws, size_t ws_size,
                              hipStream_t stream) {
  const float* x = (const float*)d_in[0];
  const int* labels = (const int*)d_in[1];
  const int* idx_train = (const int*)d_in[2];
  const float* gat_W = (const float*)d_in[3];
  const float* gat_a1 = (const float*)d_in[4];
  const float* gat_a2 = (const float*)d_in[5];
  const float* gcnW[3] = {(const float*)d_in[6], (const float*)d_in[8], (const float*)d_in[10]};
  const float* gcnB[3] = {(const float*)d_in[7], (const float*)d_in[9], (const float*)d_in[11]};
  const float* pw1[3] = {(const float*)d_in[12], (const float*)d_in[15], (const float*)d_in[18]};
  const float* pw2[3] = {(const float*)d_in[13], (const float*)d_in[16], (const float*)d_in[19]};
  const float* pbb[3] = {(const float*)d_in[14], (const float*)d_in[17], (const float*)d_in[20]};
  const float* wih = (const float*)d_in[21];
  const float* whh = (const float*)d_in[22];
  const float* bih = (const float*)d_in[23];
  const float* bhh = (const float*)d_in[24];
  const float* c1W = (const float*)d_in[25]; const float* c1b = (const float*)d_in[26];
  const float* c2W = (const float*)d_in[27]; const float* c2b = (const float*)d_in[28];
  const float* c3W = (const float*)d_in[29]; const float* c3b = (const float*)d_in[30];
  const float* fc0W = (const float*)d_in[31]; const float* fc0b = (const float*)d_in[32];
  const float* bn0g = (const float*)d_in[33]; const float* bn0b = (const float*)d_in[34];
  const float* fc1W = (const float*)d_in[35]; const float* fc1b = (const float*)d_in[36];
  const float* aW1 = (const float*)d_in[37]; const float* ab1 = (const float*)d_in[38];
  const float* aW2 = (const float*)d_in[39]; const float* ab2 = (const float*)d_in[40];
  float* out = (float*)d_out;
  float* ws = (float*)d_ws;

  // ---- workspace layout (floats). ws evidence: ~268 MB available. ----
  size_t off = 0;
  auto take = [&](size_t n) { size_t o = off; off += (n + 63) & ~(size_t)63; return o; };
  float* wa1   = ws + take(512);
  float* wa2   = ws + take(512);
  float* dinv  = ws + take(BB * 64);
  float* rbuf  = ws + take(BB * 256);
  float* xconv = ws + take(BB * 128);      // memset region start
  float* csum  = ws + take(256);
  float* csum2 = ws + take(256);           // memset region end (contiguous)
  float* hm    = ws + take(BB * 256);
  float* zb    = ws + take(BB * 128);
  float* protos = ws + take(NC * 128);
  float* lgts  = ws + take(NC * 256);
  float* ysf   = ws + take(1048576);       // ys f16: 256*64*128 halfs
  float* gw1h  = ws + take(256 * 128);
  float* gw2h  = ws + take(64 * 128);
  float* gw3h  = ws + take(64 * 128);
  float* wpkf  = ws + take(192 * 128);
  float* wihThf = ws + take(98304);        // frag-packed wih^T
  float* wtcf  = ws + take(98304);         // conv frags
  float* cv1f  = ws + take(8503296);       // conv1 out: 256*519*128 halfs (full batch)
  float* cv2f  = ws + take(8634368);       // conv2 out: 256*527*128 halfs (full batch)
  float* Z     = ws + take(8568832);       // GNN phase + gi (f32)
  // GNN-phase aliases
  float* mA  = Z;
  float* mB  = Z + 1048576;
  float* xw  = Z + 2097152;
  float* gp1 = Z + 6291456;
  float* gp2 = Z + 7340032;
  // GRU-phase alias: gi f32 at Z+0 (GNN buffers dead by then)
  float* gi = Z;
  _Float16* ysh = (_Float16*)ysf;
  unsigned int* wpk = (unsigned int*)wpkf;
  unsigned int* wihTh = (unsigned int*)wihThf;
  unsigned int* wt1h = (unsigned int*)wtcf;            // 32768
  unsigned int* wt2h = wt1h + 32768;                   // 40960
  unsigned int* wt3h = wt2h + 40960;                   // 24576

  // single memset: xconv + csum + csum2 (contiguous)
  hipMemsetAsync(xconv, 0, (BB * 128 + 512) * sizeof(float), stream);

  // ---- all weight packing + gat wa vectors ----
  k_packall<<<1058, 256, 0, stream>>>(gcnW[0], gcnW[1], gcnW[2], wih, whh,
                                      c1W, c2W, c3W, gat_W, gat_a1, gat_a2,
                                      (unsigned int*)gw1h, (unsigned int*)gw2h,
                                      (unsigned int*)gw3h, wihTh, wpk,
                                      wt1h, wt2h, wt3h, wa1, wa2);

  // ---- fused GAT adjacency ----
  k_gat<<<BB, 256, 0, stream>>>(x, wa1, wa2, mA, dinv);

  // ---- 3x (xw GEMM + fused GCN-agg/pool) ----
  k_gmfma<<<BB * 64 / 64, 256, 0, stream>>>(x, (const uint4*)gw1h, xw, BB * 64, HH, 512, 0);
  k_gcnpool<64, 32><<<BB, 256, 0, stream>>>(xw, mA, dinv, gcnB[0], pw1[0], pw2[0], pbb[0],
                                            gp1, mB, dinv, rbuf, 0);
  k_gmfma<<<BB * 32 / 64, 256, 0, stream>>>(gp1, (const uint4*)gw2h, xw, BB * 32, HH, 128, 0);
  k_gcnpool<32, 16><<<BB, 256, 0, stream>>>(xw, mB, dinv, gcnB[1], pw1[1], pw2[1], pbb[1],
                                            gp2, mA, dinv, rbuf, 1);
  k_gmfma<<<BB * 16 / 64, 256, 0, stream>>>(gp2, (const uint4*)gw3h, xw, BB * 16, HH, 128, 0);
  k_gcnpool<16, 8><<<BB, 256, 0, stream>>>(xw, mA, dinv, gcnB[2], pw1[2], pw2[2], pbb[2],
                                           nullptr, mB, nullptr, rbuf, 1);

  // ---- GRU branch: gi f32 via MFMA GEMM (into Z), recurrence -> ys f16 ----
  k_gmfma<<<(BB * CC / 64) * 3, 256, 0, stream>>>(
      x, (const uint4*)wihTh, gi, BB * CC, G3, LL, 0);
  k_gru<<<CC, 256, 0, stream>>>(gi, wpk, bhh, bih, ysh);

  // ---- dilated conv branch: full batch, 3 launches ----
  k_cmfma<64, 8, 1, 7, 512, CL1, 0><<<BB * 9, 256, 0, stream>>>(
      x, (const uint4*)wt1h, c1b, cv1f, 0);
  k_cmfma<128, 5, 2, 8, CL1, CL2, 1><<<BB * 9, 256, 0, stream>>>(
      cv1f, (const uint4*)wt2h, c2b, cv2f, 0);
  k_cmfma<128, 3, 4, 8, CL2, CL3, 2><<<BB * 9, 256, 0, stream>>>(
      cv2f, (const uint4*)wt3h, c3b, xconv, 0);

  // ---- mapping MLP + attention + distances ----
  k_fc0<<<BB, 256, 0, stream>>>(xconv, ysh, rbuf, fc0W, fc0b, hm, csum, csum2);
  k_fc1bn<<<BB, 128, 0, stream>>>(hm, csum, csum2, bn0g, bn0b, fc1W, fc1b, zb);
  k_att1<<<NC * 4, 256, 0, stream>>>(zb, aW1, ab1, aW2, lgts);
  k_att2<<<NC, 256, 0, stream>>>(zb, labels, idx_train, in_sizes[2], lgts, ab2, protos);
  k_dist<<<BB + 1, 128, 0, stream>>>(zb, protos, out);
}

// Round 18
// 433.703 us; speedup vs baseline: 1.0024x; 1.0024x over previous
//
#include <hip/hip_runtime.h>
#include <math.h>

#define BB 256   // batch
#define CC 64    // channels / graph nodes
#define LL 512   // series length
#define HH 128   // gcn hidden
#define G3 384   // 3*gru_dim
#define NC 8
#define AT 64
#define CL1 519
#define CL2 527
#define CL3 535
#define THRESH 0.02f

typedef _Float16 h2 __attribute__((ext_vector_type(2)));
typedef _Float16 f16x8 __attribute__((ext_vector_type(8)));
typedef float f32x4 __attribute__((ext_vector_type(4)));
union HU { unsigned int u; h2 h; float f; };
union BU { uint4 u; f16x8 h; };

__device__ inline float warp_red_sum(float v) {
  #pragma unroll
  for (int o = 32; o > 0; o >>= 1) v += __shfl_down(v, o, 64);
  return v;
}

__device__ inline float fdot2f(h2 a, h2 b, float c) {
#if __has_builtin(__builtin_amdgcn_fdot2)
  return __builtin_amdgcn_fdot2(a, b, c, false);
#else
  float r;
  asm volatile("v_dot2_f32_f16 %0, %1, %2, %3" : "=v"(r) : "v"(a), "v"(b), "v"(c));
  return r;
#endif
}
__device__ inline h2 asH2(float f) { HU u; u.f = f; return u.h; }
__device__ inline h2 uH2(unsigned int x) { HU u; u.u = x; return u.h; }
__device__ inline unsigned int packh(float a, float b) {
  HU u; h2 t; t.x = (_Float16)a; t.y = (_Float16)b; u.h = t; return u.u;
}
// hardware exp2 / rcp (1-ulp; continuous paths only, never near discrete thresholds)
__device__ inline float vexp2(float x) { float r; asm("v_exp_f32 %0, %1" : "=v"(r) : "v"(x)); return r; }
__device__ inline float vrcp(float x)  { float r; asm("v_rcp_f32 %0, %1" : "=v"(r) : "v"(x)); return r; }
__device__ inline float fsigm(float x) { return vrcp(1.f + vexp2(-1.44269504f * x)); }
__device__ inline float ftanh(float x) { return 1.f - 2.f * vrcp(vexp2(2.88539008f * x) + 1.f); }

// conv weights -> MFMA B-fragment-linear layout (tap decode)
__device__ inline void packw_one(const float* __restrict__ W, unsigned int* __restrict__ out,
                                 int idx, int cinlog, int KS) {
  int w_ = idx & 3, l = (idx >> 2) & 63, n = (idx >> 8) & 7, c = idx >> 11;
  int CIN = 1 << cinlog;
  int oc = n * 16 + (l & 15);
  int k0 = c * 32 + ((l >> 4) << 3) + 2 * w_;
  int t0 = k0 >> cinlog, ci0 = k0 & (CIN - 1);
  int t1 = (k0 + 1) >> cinlog, ci1 = (k0 + 1) & (CIN - 1);
  out[idx] = packh(W[(size_t)oc * CIN * KS + ci0 * KS + t0],
                   W[(size_t)oc * CIN * KS + ci1 * KS + t1]);
}

// ---- ONE pack kernel: gcn weights + wih^T + whh + conv weights + gat wa vectors ----
__global__ void k_packall(const float* __restrict__ gcnW0, const float* __restrict__ gcnW1,
                          const float* __restrict__ gcnW2, const float* __restrict__ wih,
                          const float* __restrict__ whh,
                          const float* __restrict__ c1W, const float* __restrict__ c2W,
                          const float* __restrict__ c3W,
                          const float* __restrict__ gatW, const float* __restrict__ a1,
                          const float* __restrict__ a2,
                          unsigned int* gw1h, unsigned int* gw2h, unsigned int* gw3h,
                          unsigned int* wihTh, unsigned int* wpk,
                          unsigned int* wt1h, unsigned int* wt2h, unsigned int* wt3h,
                          float* wa1, float* wa2) {
  int idx = blockIdx.x * 256 + threadIdx.x;
  if (idx < 32768) {
    int w_ = idx & 3, l = (idx >> 2) & 63, n = (idx >> 8) & 7, c = idx >> 11;
    int k0 = c * 32 + ((l >> 4) << 3) + 2 * w_;
    int col = n * 16 + (l & 15);
    gw1h[idx] = packh(gcnW0[k0 * 128 + col], gcnW0[(k0 + 1) * 128 + col]);
  } else if (idx < 40960) {
    int t = idx - 32768;
    int w_ = t & 3, l = (t >> 2) & 63, n = (t >> 8) & 7, c = t >> 11;
    int k0 = c * 32 + ((l >> 4) << 3) + 2 * w_;
    int col = n * 16 + (l & 15);
    gw2h[t] = packh(gcnW1[k0 * 128 + col], gcnW1[(k0 + 1) * 128 + col]);
  } else if (idx < 49152) {
    int t = idx - 40960;
    int w_ = t & 3, l = (t >> 2) & 63, n = (t >> 8) & 7, c = t >> 11;
    int k0 = c * 32 + ((l >> 4) << 3) + 2 * w_;
    int col = n * 16 + (l & 15);
    gw3h[t] = packh(gcnW2[k0 * 128 + col], gcnW2[(k0 + 1) * 128 + col]);
  } else if (idx < 147456) {
    // B = wih^T: B[k][n] = wih[n][k]; wih [384][512]; N16=24
    int t = idx - 49152;
    int w_ = t & 3, l = (t >> 2) & 63;
    int nfc = t >> 8;
    int n = nfc % 24, c = nfc / 24;
    int k0 = c * 32 + ((l >> 4) << 3) + 2 * w_;
    int col = n * 16 + (l & 15);
    wihTh[t] = packh(wih[col * 512 + k0], wih[col * 512 + k0 + 1]);
  } else if (idx < 172032) {
    int t = idx - 147456; int j = t & 127, rk = t >> 7;
    int r = rk >> 6, k2 = rk & 63;
    const float* src = whh + (size_t)(j + 128 * r) * 128 + 2 * k2;
    wpk[t] = packh(src[0], src[1]);
  } else if (idx < 204800) {
    packw_one(c1W, wt1h, idx - 172032, 6, 8);
  } else if (idx < 245760) {
    packw_one(c2W, wt2h, idx - 204800, 7, 5);
  } else if (idx < 270336) {
    packw_one(c3W, wt3h, idx - 245760, 7, 3);
  } else if (idx < 270848) {
    int l = idx - 270336;
    const float* row = gatW + l * LL;
    float s1 = 0.f, s2 = 0.f;
    for (int k = 0; k < LL; k++) { float w = row[k]; s1 += w * a1[k]; s2 += w * a2[k]; }
    wa1[l] = s1; wa2[l] = s2;
  }
}

// ---- fused GAT: per-sample block; row dots (4 lanes/row) + softmax + mask + dinv ----
__global__ __launch_bounds__(256) void k_gat(const float* __restrict__ x,
                                             const float* __restrict__ wa1,
                                             const float* __restrict__ wa2,
                                             float* __restrict__ mask,
                                             float* __restrict__ dinv) {
  __shared__ float h1s[64], h2s[64];
  int b = blockIdx.x, tid = threadIdx.x;
  int i = tid >> 2, q = tid & 3;
  const float* xr = x + ((size_t)b * 64 + i) * LL + q * 128;
  float s1 = 0.f, s2 = 0.f;
  #pragma unroll 4
  for (int k = 0; k < 128; k += 4) {
    float4 xv = *(const float4*)&xr[k];
    float4 w1 = *(const float4*)&wa1[q * 128 + k];
    float4 w2 = *(const float4*)&wa2[q * 128 + k];
    s1 += xv.x * w1.x + xv.y * w1.y + xv.z * w1.z + xv.w * w1.w;
    s2 += xv.x * w2.x + xv.y * w2.y + xv.z * w2.z + xv.w * w2.w;
  }
  s1 += __shfl_xor(s1, 1, 64); s1 += __shfl_xor(s1, 2, 64);
  s2 += __shfl_xor(s2, 1, 64); s2 += __shfl_xor(s2, 2, 64);
  if (q == 0) { h1s[i] = s1; h2s[i] = s2; }
  __syncthreads();
  float hi = h1s[i];
  float e[16];
  float mx = -3.4e38f;
  #pragma unroll
  for (int u = 0; u < 16; u++) {
    float v = hi + h2s[q * 16 + u];
    v = v < 0.f ? 0.2f * v : v;
    e[u] = v;
    mx = fmaxf(mx, v);
  }
  mx = fmaxf(mx, __shfl_xor(mx, 1, 64));
  mx = fmaxf(mx, __shfl_xor(mx, 2, 64));
  float sm = 0.f;
  #pragma unroll
  for (int u = 0; u < 16; u++) { e[u] = expf(e[u] - mx); sm += e[u]; }
  sm += __shfl_xor(sm, 1, 64); sm += __shfl_xor(sm, 2, 64);
  float cnt = 0.f;
  #pragma unroll
  for (int u = 0; u < 16; u++) {
    float mval = (e[u] / sm > THRESH) ? 1.f : 0.f;
    mask[((size_t)b * 64 + i) * 64 + q * 16 + u] = mval;
    cnt += mval;
  }
  cnt += __shfl_xor(cnt, 1, 64); cnt += __shfl_xor(cnt, 2, 64);
  if (q == 0) dinv[b * 64 + i] = 1.f / sqrtf(cnt + 1.f);
}

// ---------------- MFMA GEMM: C[M,N] = A[M,K](fp32) @ Bf(fragment-packed f16) ----------------
__global__ __launch_bounds__(256) void k_gmfma(const float* __restrict__ A,
                                               const uint4* __restrict__ Bf,
                                               void* __restrict__ Cv,
                                               int M, int N, int K, int out16) {
  __shared__ _Float16 as[2][64 * 64];
  int nwg = gridDim.x, bid = blockIdx.x;
  int lb = (bid & 7) * (nwg >> 3) + (bid >> 3);
  int nbn = N >> 7;
  int bm = lb / nbn, bn = lb - bm * nbn;
  int m0 = bm * 64;
  int tid = threadIdx.x, l = tid & 63, w = tid >> 6;
  int NKT = K >> 6, NC2 = K >> 5, N16 = N >> 4;
  int nf0 = bn * 8 + 2 * w, nf1 = nf0 + 1;
  int ar = tid >> 2;
  int ac = (tid & 3) * 16;
  float4 rg[4];
  auto stageA = [&](int kt) {
    const float* src = &A[(size_t)(m0 + ar) * K + kt * 64 + ac];
    rg[0] = *(const float4*)&src[0];
    rg[1] = *(const float4*)&src[4];
    rg[2] = *(const float4*)&src[8];
    rg[3] = *(const float4*)&src[12];
  };
  auto commitA = [&](int buf) {
    int s0 = (tid & 3) * 2;
    int phys0 = (s0 ^ (ar & 7)) * 8;
    int phys1 = ((s0 + 1) ^ (ar & 7)) * 8;
    uint4 v0, v1;
    v0.x = packh(rg[0].x, rg[0].y); v0.y = packh(rg[0].z, rg[0].w);
    v0.z = packh(rg[1].x, rg[1].y); v0.w = packh(rg[1].z, rg[1].w);
    v1.x = packh(rg[2].x, rg[2].y); v1.y = packh(rg[2].z, rg[2].w);
    v1.z = packh(rg[3].x, rg[3].y); v1.w = packh(rg[3].z, rg[3].w);
    *(uint4*)&as[buf][ar * 64 + phys0] = v0;
    *(uint4*)&as[buf][ar * 64 + phys1] = v1;
  };
  f32x4 acc[4][2];
  #pragma unroll
  for (int m = 0; m < 4; m++) {
    acc[m][0] = (f32x4){0.f, 0.f, 0.f, 0.f};
    acc[m][1] = (f32x4){0.f, 0.f, 0.f, 0.f};
  }
  stageA(0); commitA(0);
  uint4 bc0 = Bf[(size_t)nf0 * 64 + l];
  uint4 bc1 = Bf[(size_t)nf1 * 64 + l];
  __syncthreads();
  for (int c = 0; c < NC2; c++) {
    int kt = c >> 1, half = c & 1;
    if (half == 0 && kt + 1 < NKT) stageA(kt + 1);
    uint4 pn0 = bc0, pn1 = bc1;
    if (c + 1 < NC2) {
      pn0 = Bf[(size_t)((c + 1) * N16 + nf0) * 64 + l];
      pn1 = Bf[(size_t)((c + 1) * N16 + nf1) * 64 + l];
    }
    int slotbase = half * 4 + (l >> 4);
    f16x8 a[4];
    #pragma unroll
    for (int m = 0; m < 4; m++) {
      int row = m * 16 + (l & 15);
      int phys = slotbase ^ (row & 7);
      a[m] = *(const f16x8*)&as[kt & 1][row * 64 + phys * 8];
    }
    BU u0, u1; u0.u = bc0; u1.u = bc1;
    #pragma unroll
    for (int m = 0; m < 4; m++) {
      acc[m][0] = __builtin_amdgcn_mfma_f32_16x16x32_f16(a[m], u0.h, acc[m][0], 0, 0, 0);
      acc[m][1] = __builtin_amdgcn_mfma_f32_16x16x32_f16(a[m], u1.h, acc[m][1], 0, 0, 0);
    }
    if (half == 1 && kt + 1 < NKT) {
      commitA((kt + 1) & 1);
      __syncthreads();
    }
    bc0 = pn0; bc1 = pn1;
  }
  if (out16) {
    _Float16* Ch = (_Float16*)Cv;
    #pragma unroll
    for (int n = 0; n < 2; n++) {
      int col = (nf0 + n) * 16 + (l & 15);
      #pragma unroll
      for (int m = 0; m < 4; m++) {
        #pragma unroll
        for (int i = 0; i < 4; i++)
          Ch[(size_t)(m0 + m * 16 + (l >> 4) * 4 + i) * N + col] = (_Float16)acc[m][n][i];
      }
    }
  } else {
    float* Cf = (float*)Cv;
    #pragma unroll
    for (int n = 0; n < 2; n++) {
      int col = (nf0 + n) * 16 + (l & 15);
      #pragma unroll
      for (int m = 0; m < 4; m++) {
        #pragma unroll
        for (int i = 0; i < 4; i++)
          Cf[(size_t)(m0 + m * 16 + (l >> 4) * 4 + i) * N + col] = acc[m][n][i];
      }
    }
  }
}

// ---- fused GCN-aggregation + SAGPool: per-sample block ----
template<int N, int KK>
__global__ __launch_bounds__(256) void k_gcnpool(const float* __restrict__ xw,
                                                 const float* __restrict__ mask,
                                                 const float* __restrict__ dinv,
                                                 const float* __restrict__ bias,
                                                 const float* __restrict__ w1,
                                                 const float* __restrict__ w2,
                                                 const float* __restrict__ pb,
                                                 float* gp, float* mnext, float* dnext,
                                                 float* __restrict__ r, int accum) {
  constexpr int RPT = (N >= 32) ? (N / 32) : 1;   // rows per thread
  constexpr int NRG = N / RPT;                    // row groups (<= 32)
  __shared__ float xs[N * 132];
  __shared__ float ms[N * 65];
  __shared__ float dv[64];
  __shared__ float d1s[64], d2s[64], sv[64], vals[32], tvs[32];
  __shared__ int idxs[32];
  int b = blockIdx.x, tid = threadIdx.x;
  for (int q = tid; q < N * 32; q += 256) {
    int i = q >> 5, fo = (q & 31) * 4;
    *(float4*)&xs[i * 132 + fo] = *(const float4*)&xw[((size_t)b * N + i) * 128 + fo];
  }
  for (int q = tid; q < N * N; q += 256) {
    int row = q / N, u = q - row * N;
    ms[row * 65 + u] = mask[(size_t)(b * N + row) * N + u];
  }
  if (tid < N) dv[tid] = dinv[b * N + tid];
  __syncthreads();
  for (int q = tid; q < N * 32; q += 256) {
    int i = q >> 5, fo = (q & 31) * 4;
    float4 v = *(float4*)&xs[i * 132 + fo];
    float d = dv[i];
    v.x *= d; v.y *= d; v.z *= d; v.w *= d;
    *(float4*)&xs[i * 132 + fo] = v;
  }
  __syncthreads();
  int ri = tid >> 3, fq = tid & 7, f0 = fq * 16;
  float g[RPT][16];
  if (ri < NRG) {
    float acc[RPT][16];
    #pragma unroll
    for (int p = 0; p < RPT; p++)
      #pragma unroll
      for (int e = 0; e < 16; e++) acc[p][e] = 0.f;
    for (int j = 0; j < N; j++) {
      float4 xa = *(const float4*)&xs[j * 132 + f0];
      float4 xb = *(const float4*)&xs[j * 132 + f0 + 4];
      float4 xc = *(const float4*)&xs[j * 132 + f0 + 8];
      float4 xd = *(const float4*)&xs[j * 132 + f0 + 12];
      #pragma unroll
      for (int p = 0; p < RPT; p++) {
        float m = ms[(ri * RPT + p) * 65 + j];
        acc[p][0] += m * xa.x;  acc[p][1] += m * xa.y;
        acc[p][2] += m * xa.z;  acc[p][3] += m * xa.w;
        acc[p][4] += m * xb.x;  acc[p][5] += m * xb.y;
        acc[p][6] += m * xb.z;  acc[p][7] += m * xb.w;
        acc[p][8] += m * xc.x;  acc[p][9] += m * xc.y;
        acc[p][10] += m * xc.z; acc[p][11] += m * xc.w;
        acc[p][12] += m * xd.x; acc[p][13] += m * xd.y;
        acc[p][14] += m * xd.z; acc[p][15] += m * xd.w;
      }
    }
    float bz[16];
    #pragma unroll
    for (int e = 0; e < 16; e++) bz[e] = bias[f0 + e];
    #pragma unroll
    for (int p = 0; p < RPT; p++) {
      int i = ri * RPT + p;
      float di = dv[i];
      float4 sa = *(const float4*)&xs[i * 132 + f0];
      float4 sb = *(const float4*)&xs[i * 132 + f0 + 4];
      float4 sc = *(const float4*)&xs[i * 132 + f0 + 8];
      float4 sd = *(const float4*)&xs[i * 132 + f0 + 12];
      float sx[16] = {sa.x, sa.y, sa.z, sa.w, sb.x, sb.y, sb.z, sb.w,
                      sc.x, sc.y, sc.z, sc.w, sd.x, sd.y, sd.z, sd.w};
      #pragma unroll
      for (int e = 0; e < 16; e++) {
        float y = di * (sx[e] + acc[p][e]) + bz[e];
        g[p][e] = y > 0.f ? y : 0.f;
      }
    }
  }
  __syncthreads();
  if (ri < NRG) {
    #pragma unroll
    for (int p = 0; p < RPT; p++) {
      int i = ri * RPT + p;
      float4 va = {g[p][0], g[p][1], g[p][2], g[p][3]};
      float4 vb = {g[p][4], g[p][5], g[p][6], g[p][7]};
      float4 vc = {g[p][8], g[p][9], g[p][10], g[p][11]};
      float4 vd = {g[p][12], g[p][13], g[p][14], g[p][15]};
      *(float4*)&xs[i * 132 + f0] = va;
      *(float4*)&xs[i * 132 + f0 + 4] = vb;
      *(float4*)&xs[i * 132 + f0 + 8] = vc;
      *(float4*)&xs[i * 132 + f0 + 12] = vd;
    }
  }
  __syncthreads();
  {
    int i = tid >> 2, q4 = tid & 3;
    if (i < N) {
      float a = 0.f, c = 0.f;
      const float* gr = &xs[i * 132 + q4 * 32];
      const float* w1p = &w1[q4 * 32];
      const float* w2p = &w2[q4 * 32];
      for (int d = 0; d < 32; d++) { float v = gr[d]; a += v * w1p[d]; c += v * w2p[d]; }
      a += __shfl_xor(a, 1, 64); a += __shfl_xor(a, 2, 64);
      c += __shfl_xor(c, 1, 64); c += __shfl_xor(c, 2, 64);
      if (q4 == 0) { d1s[i] = a; d2s[i] = c; }
    }
  }
  __syncthreads();
  if (tid < N) {
    const float* mr = &ms[tid * 65];
    float s = d1s[tid] + pb[0];
    for (int j = 0; j < N; j++) s += mr[j] * d2s[j];
    sv[tid] = s;
  }
  __syncthreads();
  if (tid < 64) {
    float myv = (tid < N) ? sv[tid] : -3.4e38f;
    int alive = (tid < N) ? 1 : 0;
    for (int t = 0; t < KK; t++) {
      float cv = alive ? myv : -3.4e38f;
      int ci = tid;
      #pragma unroll
      for (int o = 32; o > 0; o >>= 1) {
        float ov = __shfl_xor(cv, o, 64);
        int oi = __shfl_xor(ci, o, 64);
        if (ov > cv || (ov == cv && oi < ci)) { cv = ov; ci = oi; }
      }
      if (tid == ci) alive = 0;
      if (tid == 0) { idxs[t] = ci; vals[t] = cv; }
    }
  }
  __syncthreads();
  if (tid < KK) tvs[tid] = tanhf(vals[tid]);
  __syncthreads();
  if (tid < HH) {
    float mx = -3.4e38f, sm = 0.f;
    for (int t = 0; t < KK; t++) {
      float v = xs[idxs[t] * 132 + tid] * tvs[t];
      if (gp) gp[(size_t)(b * KK + t) * HH + tid] = v;
      mx = fmaxf(mx, v); sm += v;
    }
    float mres = sm / (float)KK;
    if (accum) {
      r[b * 256 + tid] += mx;
      r[b * 256 + 128 + tid] += mres;
    } else {
      r[b * 256 + tid] = mx;
      r[b * 256 + 128 + tid] = mres;
    }
  }
  for (int q = tid; q < KK * KK; q += 256) {
    int t = q / KK, u = q - t * KK;
    mnext[(size_t)(b * KK + t) * KK + u] = ms[idxs[t] * 65 + idxs[u]];
  }
  if (dnext && tid < KK) {
    float s = 0.f;
    for (int u = 0; u < KK; u++) s += ms[idxs[tid] * 65 + idxs[u]];
    dnext[b * KK + tid] = 1.0f / sqrtf(s + 1.0f);
  }
}

// GRU recurrence: 256 threads/block, K-split pairs; f32 gi; ys f16 out.
__global__ __launch_bounds__(256, 1) void k_gru(const float* __restrict__ gi,
                                                const unsigned int* __restrict__ wpk,
                                                const float* __restrict__ bhh,
                                                const float* __restrict__ bih,
                                                _Float16* __restrict__ ys) {
  __shared__ _Float16 hb[2][128];
  int c = blockIdx.x;
  int j = threadIdx.x >> 1, half = threadIdx.x & 1;
  int kb = half * 32;
  h2 w0[32], w1[32], w2[32];
  #pragma unroll
  for (int kk = 0; kk < 32; kk++) { HU u; u.u = wpk[(kb + kk) * 128 + j]; w0[kk] = u.h; }
  #pragma unroll
  for (int kk = 0; kk < 32; kk++) { HU u; u.u = wpk[(64 + kb + kk) * 128 + j]; w1[kk] = u.h; }
  #pragma unroll
  for (int kk = 0; kk < 32; kk++) { HU u; u.u = wpk[(128 + kb + kk) * 128 + j]; w2[kk] = u.h; }
  float bh0 = bhh[j], bh1 = bhh[j + 128], bh2 = bhh[j + 256];
  float bi0 = bih[j], bi1 = bih[j + 128], bi2 = bih[j + 256];
  float hprev = 0.f;
  if (half == 0) hb[0][j] = (_Float16)0.f;
  __syncthreads();
  const float* gbase = gi + (size_t)c * G3 + j;
  float g0 = gbase[0], g1 = gbase[128], g2 = gbase[256];
  int cur = 0;
  for (int b = 0; b < BB; b++) {
    float n0 = 0.f, n1 = 0.f, n2 = 0.f;
    if (b + 1 < BB) {
      const float* gn = gbase + (size_t)(b + 1) * CC * G3;
      n0 = gn[0]; n1 = gn[128]; n2 = gn[256];
    }
    float a0a = 0.f, a0b = 0.f, a1a = 0.f, a1b = 0.f, a2a = 0.f, a2b = 0.f;
    #pragma unroll
    for (int q = 0; q < 8; q++) {
      float4 hv = *(const float4*)&hb[cur][half * 64 + q * 8];
      h2 h0 = asH2(hv.x), h1 = asH2(hv.y), h2v = asH2(hv.z), h3 = asH2(hv.w);
      a0a = fdot2f(w0[q * 4 + 0], h0, a0a); a0b = fdot2f(w0[q * 4 + 1], h1, a0b);
      a0a = fdot2f(w0[q * 4 + 2], h2v, a0a); a0b = fdot2f(w0[q * 4 + 3], h3, a0b);
      a1a = fdot2f(w1[q * 4 + 0], h0, a1a); a1b = fdot2f(w1[q * 4 + 1], h1, a1b);
      a1a = fdot2f(w1[q * 4 + 2], h2v, a1a); a1b = fdot2f(w1[q * 4 + 3], h3, a1b);
      a2a = fdot2f(w2[q * 4 + 0], h0, a2a); a2b = fdot2f(w2[q * 4 + 1], h1, a2b);
      a2a = fdot2f(w2[q * 4 + 2], h2v, a2a); a2b = fdot2f(w2[q * 4 + 3], h3, a2b);
    }
    float A0 = a0a + a0b, A1 = a1a + a1b, A2 = a2a + a2b;
    A0 += __shfl_xor(A0, 1, 64);
    A1 += __shfl_xor(A1, 1, 64);
    A2 += __shfl_xor(A2, 1, 64);
    A0 += bh0; A1 += bh1; A2 += bh2;
    float rg = fsigm(g0 + bi0 + A0);
    float zg = fsigm(g1 + bi1 + A1);
    float ng = ftanh(g2 + bi2 + rg * A2);
    float hn = (1.f - zg) * ng + zg * hprev;
    hprev = hn;
    if (half == 0) {
      ys[(size_t)(b * CC + c) * 128 + j] = (_Float16)hn;
      hb[cur ^ 1][j] = (_Float16)hn;
    }
    asm volatile("s_waitcnt lgkmcnt(0)" ::: "memory");
    __builtin_amdgcn_s_barrier();
    cur ^= 1;
    g0 = n0; g1 = n1; g2 = n2;
  }
}

// ---------------- MFMA implicit-GEMM conv ----------------
template<int CIN, int KS, int DIL, int PAD, int LIN, int LOUT, int MODE>
__global__ __launch_bounds__(256) void k_cmfma(const void* __restrict__ inv,
                                               const uint4* __restrict__ Bf,
                                               const float* __restrict__ bias,
                                               void* __restrict__ outv, int b0) {
  constexpr int QN = CIN / 32;
  constexpr int NCH = KS * QN;
  constexpr int SLOTS = CIN / 8;
  constexpr int NT = (LOUT + 63) / 64;
  __shared__ _Float16 xs[72 * CIN];
  int nb = blockIdx.x / NT;
  int p0 = (blockIdx.x % NT) * 64;
  int tid = threadIdx.x;
  int l = tid & 63, w = tid >> 6;

  if constexpr (MODE == 0) {
    const float* src = (const float*)inv + (size_t)nb * CIN * LIN;
    for (int q = tid; q < (CIN / 2) * 72; q += 256) {
      int ci2 = q / 72, r = q % 72;
      int ci = 2 * ci2;
      int p = p0 - PAD + r;
      float v0 = 0.f, v1 = 0.f;
      if (p >= 0 && p < LIN) { v0 = src[ci * LIN + p]; v1 = src[(ci + 1) * LIN + p]; }
      int slot = ci >> 3;
      int phys = slot ^ (r & 7);
      *(unsigned int*)&xs[r * CIN + phys * 8 + (ci & 7)] = packh(v0, v1);
    }
  } else {
    const _Float16* src = (const _Float16*)inv + (size_t)nb * LIN * CIN;
    for (int q = tid; q < 72 * SLOTS; q += 256) {
      int r = q / SLOTS, s = q % SLOTS;
      int p = p0 - PAD + r;
      uint4 v = make_uint4(0u, 0u, 0u, 0u);
      if (p >= 0 && p < LIN) v = *(const uint4*)&src[(size_t)p * CIN + s * 8];
      int phys = s ^ (r & 7);
      *(uint4*)&xs[r * CIN + phys * 8] = v;
    }
  }
  __syncthreads();

  int n0 = 2 * w, n1 = n0 + 1;
  f32x4 acc[4][2];
  #pragma unroll
  for (int m = 0; m < 4; m++) {
    acc[m][0] = (f32x4){0.f, 0.f, 0.f, 0.f};
    acc[m][1] = (f32x4){0.f, 0.f, 0.f, 0.f};
  }
  uint4 bc0 = Bf[(size_t)(0 * 8 + n0) * 64 + l];
  uint4 bc1 = Bf[(size_t)(0 * 8 + n1) * 64 + l];
  for (int c = 0; c < NCH; c++) {
    uint4 bn0 = bc0, bn1 = bc1;
    if (c + 1 < NCH) {
      bn0 = Bf[(size_t)((c + 1) * 8 + n0) * 64 + l];
      bn1 = Bf[(size_t)((c + 1) * 8 + n1) * 64 + l];
    }
    int t = c / QN, q = c % QN;
    int slotbase = q * 4 + (l >> 4);
    f16x8 a[4];
    #pragma unroll
    for (int m = 0; m < 4; m++) {
      int r = m * 16 + (l & 15) + t * DIL;
      int phys = slotbase ^ (r & 7);
      a[m] = *(const f16x8*)&xs[r * CIN + phys * 8];
    }
    BU u0, u1; u0.u = bc0; u1.u = bc1;
    #pragma unroll
    for (int m = 0; m < 4; m++) {
      acc[m][0] = __builtin_amdgcn_mfma_f32_16x16x32_f16(a[m], u0.h, acc[m][0], 0, 0, 0);
      acc[m][1] = __builtin_amdgcn_mfma_f32_16x16x32_f16(a[m], u1.h, acc[m][1], 0, 0, 0);
    }
    bc0 = bn0; bc1 = bn1;
  }

  if constexpr (MODE == 2) {
    float* xcv = (float*)outv;
    #pragma unroll
    for (int n = 0; n < 2; n++) {
      int oc = (2 * w + n) * 16 + (l & 15);
      float bz = bias[oc];
      float s = 0.f;
      #pragma unroll
      for (int m = 0; m < 4; m++) {
        #pragma unroll
        for (int i = 0; i < 4; i++) {
          int pos = p0 + m * 16 + (l >> 4) * 4 + i;
          if (pos < LOUT) { float y = acc[m][n][i] + bz; s += y > 0.f ? y : 0.f; }
        }
      }
      s += __shfl_xor(s, 16, 64);
      s += __shfl_xor(s, 32, 64);
      if (l < 16) atomicAdd(&xcv[(size_t)(b0 + nb) * 128 + oc], s);
    }
  } else {
    _Float16* outp = (_Float16*)outv + (size_t)nb * LOUT * 128;
    #pragma unroll
    for (int n = 0; n < 2; n++) {
      int oc = (2 * w + n) * 16 + (l & 15);
      float bz = bias[oc];
      #pragma unroll
      for (int m = 0; m < 4; m++) {
        #pragma unroll
        for (int i = 0; i < 4; i++) {
          int pos = p0 + m * 16 + (l >> 4) * 4 + i;
          if (pos < LOUT) {
            float y = acc[m][n][i] + bz;
            outp[(size_t)pos * 128 + oc] = (_Float16)(y > 0.f ? y : 0.f);
          }
        }
      }
    }
  }
}

// fc0: fused GRU mean (ys f16) + atomic batch-norm column stats
__global__ void k_fc0(const float* __restrict__ xconv, const _Float16* __restrict__ ys,
                      const float* __restrict__ r, const float* __restrict__ W,
                      const float* __restrict__ bias, float* __restrict__ hm,
                      float* __restrict__ csum, float* __restrict__ csum2) {
  __shared__ float feat[512];
  int b = blockIdx.x, t = threadIdx.x;
  if (t < 128) {
    feat[t] = xconv[b * 128 + t] * (1.f / (float)CL3);
    const _Float16* yb = ys + (size_t)b * CC * 128 + t;
    float acc = 0.f;
    for (int c = 0; c < CC; c++) acc += (float)yb[c * 128];
    feat[128 + t] = acc / 64.f;
  }
  feat[256 + t] = r[b * 256 + t];
  __syncthreads();
  float acc = bias[t];
  for (int k = 0; k < 512; k++) acc += feat[k] * W[k * 256 + t];
  hm[b * 256 + t] = acc;
  atomicAdd(&csum[t], acc);
  atomicAdd(&csum2[t], acc * acc);
}

// fused batchnorm (from atomic stats) + leaky_relu + fc1
__global__ void k_fc1bn(const float* __restrict__ hm, const float* __restrict__ csum,
                        const float* __restrict__ csum2, const float* __restrict__ gamma,
                        const float* __restrict__ beta, const float* __restrict__ W,
                        const float* __restrict__ bias, float* __restrict__ z) {
  __shared__ float hs[256];
  int b = blockIdx.x, t = threadIdx.x;   // 128 threads
  for (int kk = t; kk < 256; kk += 128) {
    float v = hm[b * 256 + kk];
    float mean = csum[kk] * (1.f / 256.f);
    float var = csum2[kk] * (1.f / 256.f) - mean * mean;
    float y = gamma[kk] * (v - mean) * (1.f / sqrtf(var + 1e-5f)) + beta[kk];
    hs[kk] = y < 0.f ? 0.01f * y : y;
  }
  __syncthreads();
  float acc = bias[t];
  for (int k = 0; k < 256; k++) acc += hs[k] * W[k * 128 + t];
  z[b * 128 + t] = acc;
}

// attention logits: grid (8 classes x 4 sample-tiles of 64)
__global__ __launch_bounds__(256) void k_att1(const float* __restrict__ z,
                                              const float* __restrict__ W1,
                                              const float* __restrict__ b1,
                                              const float* __restrict__ W2,
                                              float* __restrict__ logits) {
  __shared__ float sa[32][64];
  __shared__ float sb[32][64];
  int c = blockIdx.x >> 2;
  int m0 = (blockIdx.x & 3) * 64;
  const float* B = W1 + (size_t)c * 128 * AT;
  int tx = threadIdx.x & 15, ty = threadIdx.x >> 4;
  float acc[4][4];
  #pragma unroll
  for (int i = 0; i < 4; i++)
    #pragma unroll
    for (int j = 0; j < 4; j++) acc[i][j] = 0.f;
  int arow = threadIdx.x >> 2;
  int acol = (threadIdx.x & 3) * 8;
  int brow = threadIdx.x >> 4;
  int bcol = (threadIdx.x & 15) * 4;
  for (int k0 = 0; k0 < 128; k0 += 32) {
    float4 av0 = *(const float4*)&z[(size_t)(m0 + arow) * 128 + k0 + acol];
    float4 av1 = *(const float4*)&z[(size_t)(m0 + arow) * 128 + k0 + acol + 4];
    float4 bv0 = *(const float4*)&B[(size_t)(k0 + brow) * AT + bcol];
    float4 bv1 = *(const float4*)&B[(size_t)(k0 + brow + 16) * AT + bcol];
    __syncthreads();
    sa[acol + 0][arow] = av0.x; sa[acol + 1][arow] = av0.y;
    sa[acol + 2][arow] = av0.z; sa[acol + 3][arow] = av0.w;
    sa[acol + 4][arow] = av1.x; sa[acol + 5][arow] = av1.y;
    sa[acol + 6][arow] = av1.z; sa[acol + 7][arow] = av1.w;
    *(float4*)&sb[brow][bcol] = bv0;
    *(float4*)&sb[brow + 16][bcol] = bv1;
    __syncthreads();
    #pragma unroll
    for (int kk = 0; kk < 32; kk++) {
      float4 a4 = *(const float4*)&sa[kk][ty * 4];
      float4 b4 = *(const float4*)&sb[kk][tx * 4];
      acc[0][0] += a4.x * b4.x; acc[0][1] += a4.x * b4.y; acc[0][2] += a4.x * b4.z; acc[0][3] += a4.x * b4.w;
      acc[1][0] += a4.y * b4.x; acc[1][1] += a4.y * b4.y; acc[1][2] += a4.y * b4.z; acc[1][3] += a4.y * b4.w;
      acc[2][0] += a4.z * b4.x; acc[2][1] += a4.z * b4.y; acc[2][2] += a4.z * b4.z; acc[2][3] += a4.z * b4.w;
      acc[3][0] += a4.w * b4.x; acc[3][1] += a4.w * b4.y; acc[3][2] += a4.w * b4.z; acc[3][3] += a4.w * b4.w;
    }
  }
  const float* b1c = b1 + c * AT;
  const float* w2c = W2 + c * AT;
  float w2v[4], b1v[4];
  #pragma unroll
  for (int j = 0; j < 4; j++) { w2v[j] = w2c[tx * 4 + j]; b1v[j] = b1c[tx * 4 + j]; }
  #pragma unroll
  for (int i = 0; i < 4; i++) {
    float s = 0.f;
    #pragma unroll
    for (int j = 0; j < 4; j++) s += tanhf(acc[i][j] + b1v[j]) * w2v[j];
    #pragma unroll
    for (int o = 8; o > 0; o >>= 1) s += __shfl_xor(s, o, 64);
    if (tx == 0) logits[c * 256 + m0 + ty * 4 + i] = s;
  }
}

// masked softmax over samples + prototype
__global__ void k_att2(const float* __restrict__ z, const int* __restrict__ labels,
                       const int* __restrict__ idx_train, int ntrain,
                       const float* __restrict__ logits, const float* __restrict__ b2,
                       float* __restrict__ protos) {
  __shared__ float wv[256], red[256];
  __shared__ int trainm[256];
  int c = blockIdx.x, n = threadIdx.x;
  trainm[n] = 0; __syncthreads();
  if (n < ntrain) trainm[idx_train[n]] = 1;
  __syncthreads();
  bool keep = trainm[n] && (labels[n] == c);
  float ml = keep ? (logits[c * 256 + n] + b2[c]) : -1e30f;
  red[n] = ml; __syncthreads();
  for (int s = 128; s > 0; s >>= 1) { if (n < s) red[n] = fmaxf(red[n], red[n + s]); __syncthreads(); }
  float mx = red[0]; __syncthreads();
  float e = expf(ml - mx);
  wv[n] = e; red[n] = e; __syncthreads();
  for (int s = 128; s > 0; s >>= 1) { if (n < s) red[n] += red[n + s]; __syncthreads(); }
  float ssum = red[0]; __syncthreads();
  wv[n] = wv[n] / ssum;
  __syncthreads();
  if (n < 128) {
    float p = 0.f;
    for (int q = 0; q < 256; q++) p += wv[q] * z[q * 128 + n];
    protos[c * 128 + n] = p;
  }
}

// distances; block BB does the prototype-pair term
__global__ void k_dist(const float* __restrict__ z, const float* __restrict__ protos,
                       float* __restrict__ dout) {
  if (blockIdx.x == BB) {
    int t = threadIdx.x;
    if (t < 64) {
      int i = t >> 3, jx = t & 7;
      float dot = 0.f, p2i = 0.f, p2j = 0.f;
      for (int d = 0; d < 128; d++) {
        float a = protos[i * 128 + d], bb2 = protos[jx * 128 + d];
        dot += a * bb2; p2i += a * a; p2j += bb2 * bb2;
      }
      float d2 = fmaxf(p2i + p2j - 2.f * dot, 1e-12f);
      float e = expf(-0.5f * sqrtf(d2));
      e = warp_red_sum(e);
      if (t == 0) dout[2048] = e / 28.f;
    }
    return;
  }
  __shared__ float zs[128], red[128];
  int n = blockIdx.x, t = threadIdx.x;
  zs[t] = z[n * 128 + t];
  red[t] = zs[t] * zs[t]; __syncthreads();
  for (int s = 64; s > 0; s >>= 1) { if (t < s) red[t] += red[t + s]; __syncthreads(); }
  float z2 = red[0];
  if (t < NC) {
    float dot = 0.f, p2 = 0.f;
    const float* pr = protos + t * 128;
    for (int d = 0; d < 128; d++) { float pv = pr[d]; dot += pv * zs[d]; p2 += pv * pv; }
    float d2 = fmaxf(z2 + p2 - 2.f * dot, 1e-12f);
    dout[n * NC + t] = expf(-0.5f * sqrtf(d2));
  }
}

extern "C" void kernel_launch(void* const* d_in, const int* in_sizes, int n_in,
                              void* d_out, int out_size, void* d_ws, size_t ws_size,
                              hipStream_t stream) {
  const float* x = (const float*)d_in[0];
  const int* labels = (const int*)d_in[1];
  const int* idx_train = (const int*)d_in[2];
  const float* gat_W = (const float*)d_in[3];
  const float* gat_a1 = (const float*)d_in[4];
  const float* gat_a2 = (const float*)d_in[5];
  const float* gcnW[3] = {(const float*)d_in[6], (const float*)d_in[8], (const float*)d_in[10]};
  const float* gcnB[3] = {(const float*)d_in[7], (const float*)d_in[9], (const float*)d_in[11]};
  const float* pw1[3] = {(const float*)d_in[12], (const float*)d_in[15], (const float*)d_in[18]};
  const float* pw2[3] = {(const float*)d_in[13], (const float*)d_in[16], (const float*)d_in[19]};
  const float* pbb[3] = {(const float*)d_in[14], (const float*)d_in[17], (const float*)d_in[20]};
  const float* wih = (const float*)d_in[21];
  const float* whh = (const float*)d_in[22];
  const float* bih = (const float*)d_in[23];
  const float* bhh = (const float*)d_in[24];
  const float* c1W = (const float*)d_in[25]; const float* c1b = (const float*)d_in[26];
  const float* c2W = (const float*)d_in[27]; const float* c2b = (const float*)d_in[28];
  const float* c3W = (const float*)d_in[29]; const float* c3b = (const float*)d_in[30];
  const float* fc0W = (const float*)d_in[31]; const float* fc0b = (const float*)d_in[32];
  const float* bn0g = (const float*)d_in[33]; const float* bn0b = (const float*)d_in[34];
  const float* fc1W = (const float*)d_in[35]; const float* fc1b = (const float*)d_in[36];
  const float* aW1 = (const float*)d_in[37]; const float* ab1 = (const float*)d_in[38];
  const float* aW2 = (const float*)d_in[39]; const float* ab2 = (const float*)d_in[40];
  float* out = (float*)d_out;
  float* ws = (float*)d_ws;

  // ---- workspace layout (floats). ws evidence: ~268 MB available. ----
  size_t off = 0;
  auto take = [&](size_t n) { size_t o = off; off += (n + 63) & ~(size_t)63; return o; };
  float* wa1   = ws + take(512);
  float* wa2   = ws + take(512);
  float* dinv  = ws + take(BB * 64);
  float* rbuf  = ws + take(BB * 256);
  float* xconv = ws + take(BB * 128);      // memset region start
  float* csum  = ws + take(256);
  float* csum2 = ws + take(256);           // memset region end (contiguous)
  float* hm    = ws + take(BB * 256);
  float* zb    = ws + take(BB * 128);
  float* protos = ws + take(NC * 128);
  float* lgts  = ws + take(NC * 256);
  float* ysf   = ws + take(1048576);       // ys f16: 256*64*128 halfs
  float* gw1h  = ws + take(256 * 128);
  float* gw2h  = ws + take(64 * 128);
  float* gw3h  = ws + take(64 * 128);
  float* wpkf  = ws + take(192 * 128);
  float* wihThf = ws + take(98304);        // frag-packed wih^T
  float* wtcf  = ws + take(98304);         // conv frags
  float* cv1f  = ws + take(8503296);       // conv1 out: 256*519*128 halfs (full batch)
  float* cv2f  = ws + take(8634368);       // conv2 out: 256*527*128 halfs (full batch)
  float* Z     = ws + take(8568832);       // GNN phase + gi (f32)
  // GNN-phase aliases
  float* mA  = Z;
  float* mB  = Z + 1048576;
  float* xw  = Z + 2097152;
  float* gp1 = Z + 6291456;
  float* gp2 = Z + 7340032;
  // GRU-phase alias: gi f32 at Z+0 (GNN buffers dead by then)
  float* gi = Z;
  _Float16* ysh = (_Float16*)ysf;
  unsigned int* wpk = (unsigned int*)wpkf;
  unsigned int* wihTh = (unsigned int*)wihThf;
  unsigned int* wt1h = (unsigned int*)wtcf;            // 32768
  unsigned int* wt2h = wt1h + 32768;                   // 40960
  unsigned int* wt3h = wt2h + 40960;                   // 24576

  // single memset: xconv + csum + csum2 (contiguous)
  hipMemsetAsync(xconv, 0, (BB * 128 + 512) * sizeof(float), stream);

  // ---- all weight packing + gat wa vectors ----
  k_packall<<<1058, 256, 0, stream>>>(gcnW[0], gcnW[1], gcnW[2], wih, whh,
                                      c1W, c2W, c3W, gat_W, gat_a1, gat_a2,
                                      (unsigned int*)gw1h, (unsigned int*)gw2h,
                                      (unsigned int*)gw3h, wihTh, wpk,
                                      wt1h, wt2h, wt3h, wa1, wa2);

  // ---- fused GAT adjacency ----
  k_gat<<<BB, 256, 0, stream>>>(x, wa1, wa2, mA, dinv);

  // ---- 3x (xw GEMM + fused GCN-agg/pool) ----
  k_gmfma<<<BB * 64 / 64, 256, 0, stream>>>(x, (const uint4*)gw1h, xw, BB * 64, HH, 512, 0);
  k_gcnpool<64, 32><<<BB, 256, 0, stream>>>(xw, mA, dinv, gcnB[0], pw1[0], pw2[0], pbb[0],
                                            gp1, mB, dinv, rbuf, 0);
  k_gmfma<<<BB * 32 / 64, 256, 0, stream>>>(gp1, (const uint4*)gw2h, xw, BB * 32, HH, 128, 0);
  k_gcnpool<32, 16><<<BB, 256, 0, stream>>>(xw, mB, dinv, gcnB[1], pw1[1], pw2[1], pbb[1],
                                            gp2, mA, dinv, rbuf, 1);
  k_gmfma<<<BB * 16 / 64, 256, 0, stream>>>(gp2, (const uint4*)gw3h, xw, BB * 16, HH, 128, 0);
  k_gcnpool<16, 8><<<BB, 256, 0, stream>>>(xw, mA, dinv, gcnB[2], pw1[2], pw2[2], pbb[2],
                                           nullptr, mB, nullptr, rbuf, 1);

  // ---- GRU branch: gi f32 via MFMA GEMM (into Z), recurrence -> ys f16 ----
  k_gmfma<<<(BB * CC / 64) * 3, 256, 0, stream>>>(
      x, (const uint4*)wihTh, gi, BB * CC, G3, LL, 0);
  k_gru<<<CC, 256, 0, stream>>>(gi, wpk, bhh, bih, ysh);

  // ---- dilated conv branch: full batch, 3 launches ----
  k_cmfma<64, 8, 1, 7, 512, CL1, 0><<<BB * 9, 256, 0, stream>>>(
      x, (const uint4*)wt1h, c1b, cv1f, 0);
  k_cmfma<128, 5, 2, 8, CL1, CL2, 1><<<BB * 9, 256, 0, stream>>>(
      cv1f, (const uint4*)wt2h, c2b, cv2f, 0);
  k_cmfma<128, 3, 4, 8, CL2, CL3, 2><<<BB * 9, 256, 0, stream>>>(
      cv2f, (const uint4*)wt3h, c3b, xconv, 0);

  // ---- mapping MLP + attention + distances ----
  k_fc0<<<BB, 256, 0, stream>>>(xconv, ysh, rbuf, fc0W, fc0b, hm, csum, csum2);
  k_fc1bn<<<BB, 128, 0, stream>>>(hm, csum, csum2, bn0g, bn0b, fc1W, fc1b, zb);
  k_att1<<<NC * 4, 256, 0, stream>>>(zb, aW1, ab1, aW2, lgts);
  k_att2<<<NC, 256, 0, stream>>>(zb, labels, idx_train, in_sizes[2], lgts, ab2, protos);
  k_dist<<<BB + 1, 128, 0, stream>>>(zb, protos, out);
}